// Round 5
// baseline (451.795 us; speedup 1.0000x reference)
//
#include <hip/hip_runtime.h>
#include <hip/hip_bf16.h>
#include <math.h>

#define CB 8
#define CC 256
#define CH 96
#define CWD 96
#define CL 144           // windows per image (12*12)
#define CN 1152          // total windows
#define CQ 64            // queries per window (8*8)
#define NHEADS 8
#define HD 32
#define HWSZ (CH*CWD)    // 9216
#define QSCALE 0.17677669529663687f   // 32^-0.5
#define NSLICE 32        // pool split-K slices (8 channels each)

typedef __attribute__((ext_vector_type(4))) float  f32x4;
typedef __attribute__((ext_vector_type(4))) short  s16x4;
typedef __attribute__((ext_vector_type(8))) short  s16x8;
typedef __attribute__((ext_vector_type(8))) __bf16 bf16x8;

// native RNE fp32 -> bf16 (v_cvt_pk_bf16_f32 on gfx950)
static __device__ __forceinline__ short f2b(float f) {
  __hip_bfloat16 h = __float2bfloat16(f);
  return __builtin_bit_cast(short, h);
}

static __device__ __forceinline__ bf16x8 pack8(float4 lo, float4 hi) {
  union { __hip_bfloat162 h2[4]; s16x8 v; } u;
  u.h2[0] = __float22bfloat162_rn(make_float2(lo.x, lo.y));
  u.h2[1] = __float22bfloat162_rn(make_float2(lo.z, lo.w));
  u.h2[2] = __float22bfloat162_rn(make_float2(hi.x, hi.y));
  u.h2[3] = __float22bfloat162_rn(make_float2(hi.z, hi.w));
  return __builtin_bit_cast(bf16x8, u.v);
}

static __device__ __forceinline__ s16x4 pack4(float4 v) {
  union { __hip_bfloat162 h2[2]; s16x4 v; } u;
  u.h2[0] = __float22bfloat162_rn(make_float2(v.x, v.y));
  u.h2[1] = __float22bfloat162_rn(make_float2(v.z, v.w));
  return u.v;
}

// ---------------------------------------------------------------------------
// K0: fp32 -> bf16 bulk convert (8 elems / thread)
// ---------------------------------------------------------------------------
__global__ __launch_bounds__(256) void k_cvt(const float* __restrict__ s,
                                             short* __restrict__ d, int n8) {
  int i = blockIdx.x * 256 + threadIdx.x;
  if (i >= n8) return;
  const float4* p = (const float4*)s + (size_t)i * 2;
  *(s16x8*)(d + (size_t)i * 8) = __builtin_bit_cast(s16x8, pack8(p[0], p[1]));
}

// ---------------------------------------------------------------------------
// K0b: pool_w -> bf16, K-blocked fragment-native layout.
//   pw2[((ks*16 + kc)*256 + o)*32 + kk] = bf16( pw[o][ks*512 + kc*32 + kk] )
// ---------------------------------------------------------------------------
__global__ __launch_bounds__(256) void k_cvtp(const float* __restrict__ pw,
                                              short* __restrict__ pw2) {
  int g = blockIdx.x * 256 + threadIdx.x;      // 524288 groups of 8
  int kk8 = (g & 3) * 8;
  int o   = (g >> 2) & 255;
  int kc  = (g >> 10) & 15;
  int ks  = g >> 14;
  int kglob = ks * 512 + kc * 32 + kk8;
  const float* src = pw + (size_t)o * 16384 + kglob;  // 8 contiguous floats
  *(s16x8*)(pw2 + (size_t)g * 8) =
      __builtin_bit_cast(s16x8, pack8(*(const float4*)src, *(const float4*)(src + 4)));
}

// ---------------------------------------------------------------------------
// K1 (MFMA v4): pool partial GEMM, split-K x32.
//   grid (36 rowblk, 32 kslice) = 1152 blocks. Block = 32 windows x 256 cols.
//   Waves COLUMN-split (64 cols each): B-frags unique per wave (no x4 dup),
//   A shared across waves via L1. x fetched exactly once over the grid.
// ---------------------------------------------------------------------------
__global__ __launch_bounds__(256) void k_pool(const float* __restrict__ x,
                                              const short* __restrict__ pw2,
                                              float* __restrict__ part) {
  const int t = threadIdx.x, lane = t & 63, w = t >> 6;
  const int col = lane & 15, quad = lane >> 4;
  const int mb = blockIdx.x, ks = blockIdx.y;

  size_t xbase[2];
#pragma unroll
  for (int rt = 0; rt < 2; ++rt) {
    int wdx = mb * 32 + rt * 16 + col;
    int b = wdx / CL, l = wdx - b * CL;
    int wh = l / 12, ww = l - wh * 12;
    xbase[rt] = (size_t)b * CC * HWSZ + wh * 8 * CWD + ww * 8;
  }

  f32x4 acc[2][4] = {};

#pragma unroll 4
  for (int kc = 0; kc < 16; ++kc) {
    const int c = ks * 8 + (kc >> 1);
    const int i = (kc & 1) * 4 + quad;
    bf16x8 af[2];
#pragma unroll
    for (int rt = 0; rt < 2; ++rt) {
      const float* ap = x + xbase[rt] + (size_t)c * HWSZ + i * CWD;
      af[rt] = pack8(*(const float4*)ap, *(const float4*)(ap + 4));
    }
    const short* bk = pw2 + ((size_t)(ks * 16 + kc) * 256 + w * 64) * 32;
#pragma unroll
    for (int ct = 0; ct < 4; ++ct) {
      s16x8 rb = *(const s16x8*)(bk + (ct * 16 + col) * 32 + quad * 8);
      bf16x8 bf = __builtin_bit_cast(bf16x8, rb);
#pragma unroll
      for (int rt = 0; rt < 2; ++rt)
        acc[rt][ct] = __builtin_amdgcn_mfma_f32_16x16x32_bf16(af[rt], bf, acc[rt][ct], 0, 0, 0);
    }
  }

  float* pp = part + ((size_t)ks * CN + mb * 32) * CC + w * 64;
#pragma unroll
  for (int rt = 0; rt < 2; ++rt)
#pragma unroll
    for (int ct = 0; ct < 4; ++ct)
#pragma unroll
      for (int r = 0; r < 4; ++r)
        pp[(rt * 16 + quad * 4 + r) * CC + ct * 16 + col] = acc[rt][ct][r];
}

// ---------------------------------------------------------------------------
// K1b: reduce 32 partials + bias -> pxr[1152][256]
// ---------------------------------------------------------------------------
__global__ __launch_bounds__(256) void k_poolred(const float* __restrict__ part,
                                                 const float* __restrict__ pbv,
                                                 float* __restrict__ pxr) {
  int base = (blockIdx.x * 256 + threadIdx.x) * 4;
  int m = base & 255;
  float4 s = *(const float4*)&pbv[m];
#pragma unroll
  for (int ss = 0; ss < NSLICE; ++ss) {
    float4 p = *(const float4*)&part[(size_t)ss * (CN * CC) + base];
    s.x += p.x; s.y += p.y; s.z += p.z; s.w += p.w;
  }
  *(float4*)&pxr[base] = s;
}

// ---------------------------------------------------------------------------
// K2: kv GEMM [1152,256] @ Wkv^T -> scatter to k[b,h,l,d], v[b,h,l,d]  (fp32)
// ---------------------------------------------------------------------------
__global__ __launch_bounds__(256) void k_kv(const float* __restrict__ pxr,
                                            const float* __restrict__ wkv,
                                            float* __restrict__ kbuf,
                                            float* __restrict__ vbuf) {
  const int t = threadIdx.x, tx = t & 15, ty = t >> 4;
  const int row0 = blockIdx.x * 64;
  const int col0 = blockIdx.y * 64;
  __shared__ float As[16][68];
  __shared__ float Bs[16][68];
  float acc[4][4] = {};
  const int ml = t & 15, rB = t >> 4;

  for (int mc = 0; mc < 16; ++mc) {
#pragma unroll
    for (int u = 0; u < 4; ++u) {
      int r = rB + 16 * u;
      As[ml][r] = pxr[(row0 + r) * CC + mc * 16 + ml];
      Bs[ml][r] = wkv[(col0 + r) * CC + mc * 16 + ml];
    }
    __syncthreads();
#pragma unroll
    for (int kk = 0; kk < 16; ++kk) {
      float4 a4 = *(const float4*)&As[kk][ty * 4];
      float4 b4 = *(const float4*)&Bs[kk][tx * 4];
      float av[4] = {a4.x, a4.y, a4.z, a4.w};
      float bv[4] = {b4.x, b4.y, b4.z, b4.w};
#pragma unroll
      for (int ri = 0; ri < 4; ++ri)
#pragma unroll
        for (int cj = 0; cj < 4; ++cj) acc[ri][cj] += av[ri] * bv[cj];
    }
    __syncthreads();
  }

#pragma unroll
  for (int ri = 0; ri < 4; ++ri) {
    int row = row0 + ty * 4 + ri;
    int b = row / CL, l = row - b * CL;
    int j = col0 + tx * 4;
    int d = j & 31, h = (j >> 5) & 7, tkv = j >> 8;
    float* dst = (tkv ? vbuf : kbuf) + ((size_t)(b * NHEADS + h) * CL + l) * HD + d;
    *(float4*)dst = make_float4(acc[ri][0], acc[ri][1], acc[ri][2], acc[ri][3]);
  }
}

// ---------------------------------------------------------------------------
// K3 (MFMA): q^T = Wq * xw^T per window; C-layout store transposes back into
//   d_out q slots.
// ---------------------------------------------------------------------------
__global__ __launch_bounds__(256) void k_q(const float* __restrict__ x,
                                           const short* __restrict__ wqb,
                                           float* __restrict__ qout) {
  const int t = threadIdx.x, lane = t & 63, w = t >> 6;
  const int col = lane & 15, quad = lane >> 4;
  const int n = blockIdx.x;
  const int b = n / CL, l = n - b * CL;
  const int wh = l / 12, ww = l - wh * 12;
  const size_t xwin = (size_t)b * CC * HWSZ + wh * 8 * CWD + ww * 8;

  __shared__ short xq[64][264];
  {
    const int ci = t & 31, ii = t >> 5;
#pragma unroll
    for (int u = 0; u < 8; ++u) {
      const float* ap = x + xwin + (size_t)(ci + 32 * u) * HWSZ + ii * CWD;
      float4 lo = *(const float4*)ap, hi = *(const float4*)(ap + 4);
      float vals[8] = {lo.x, lo.y, lo.z, lo.w, hi.x, hi.y, hi.z, hi.w};
#pragma unroll
      for (int j = 0; j < 8; ++j) xq[ii * 8 + j][ci + 32 * u] = f2b(vals[j]);
    }
  }
  __syncthreads();

  f32x4 acc[4][4] = {};
  for (int kc = 0; kc < 8; ++kc) {
    bf16x8 af[4];
#pragma unroll
    for (int cht = 0; cht < 4; ++cht) {
      s16x8 r = *(const s16x8*)(wqb + (size_t)(w * 64 + cht * 16 + col) * CC + kc * 32 + quad * 8);
      af[cht] = __builtin_bit_cast(bf16x8, r);
    }
#pragma unroll
    for (int qt = 0; qt < 4; ++qt) {
      s16x8 rb = *(const s16x8*)&xq[qt * 16 + col][kc * 32 + quad * 8];
      bf16x8 bfv = __builtin_bit_cast(bf16x8, rb);
#pragma unroll
      for (int cht = 0; cht < 4; ++cht)
        acc[cht][qt] = __builtin_amdgcn_mfma_f32_16x16x32_bf16(af[cht], bfv, acc[cht][qt], 0, 0, 0);
    }
  }

  float* op = qout + (size_t)n * CQ * CC;
#pragma unroll
  for (int qt = 0; qt < 4; ++qt)
#pragma unroll
    for (int cht = 0; cht < 4; ++cht) {
      f32x4 v = acc[cht][qt];
      *(float4*)&op[(qt * 16 + col) * CC + w * 64 + cht * 16 + quad * 4] =
          make_float4(v[0] * QSCALE, v[1] * QSCALE, v[2] * QSCALE, v[3] * QSCALE);
    }
}

// ---------------------------------------------------------------------------
// K4 (MFMA v3): attention. Block = 1 window x 512 threads (8 waves = 8 heads).
//   Block collectively touches full 1 KB q/O rows -> full cache-line use.
// ---------------------------------------------------------------------------
__global__ __launch_bounds__(512) void k_attn(const float* __restrict__ kbuf,
                                              const float* __restrict__ vbuf,
                                              float* __restrict__ S) {
  const int t = threadIdx.x;
  const int h = t >> 6, lane = t & 63;
  const int col = lane & 15, quad = lane >> 4;
  const int n = blockIdx.x;
  const int bb = n & 7;

  const float* kh = kbuf + (size_t)(bb * NHEADS + h) * CL * HD;
  const float* vh = vbuf + (size_t)(bb * NHEADS + h) * CL * HD;
  float* Sn = S + (size_t)n * (CQ * CC) + h * HD;

  bf16x8 ka[9];
#pragma unroll
  for (int lt = 0; lt < 9; ++lt) {
    const float* kr = kh + (lt * 16 + col) * HD + quad * 8;
    ka[lt] = pack8(*(const float4*)kr, *(const float4*)(kr + 4));
  }

  s16x4 vt[2][9];
#pragma unroll
  for (int dt = 0; dt < 2; ++dt)
#pragma unroll
    for (int lc = 0; lc < 9; ++lc) {
      float4 vv;
      vv.x = vh[(lc * 16 + quad * 4 + 0) * HD + dt * 16 + col];
      vv.y = vh[(lc * 16 + quad * 4 + 1) * HD + dt * 16 + col];
      vv.z = vh[(lc * 16 + quad * 4 + 2) * HD + dt * 16 + col];
      vv.w = vh[(lc * 16 + quad * 4 + 3) * HD + dt * 16 + col];
      vt[dt][lc] = pack4(vv);
    }

  const f32x4 zero = {0.f, 0.f, 0.f, 0.f};

#pragma unroll
  for (int qt = 0; qt < 4; ++qt) {
    const float* qr = Sn + (size_t)(qt * 16 + col) * CC + quad * 8;
    bf16x8 qb = pack8(*(const float4*)qr, *(const float4*)(qr + 4));

    f32x4 s[9];
#pragma unroll
    for (int lt = 0; lt < 9; ++lt)
      s[lt] = __builtin_amdgcn_mfma_f32_16x16x32_bf16(ka[lt], qb, zero, 0, 0, 0);

    float mx = s[0][0];
#pragma unroll
    for (int lt = 0; lt < 9; ++lt)
#pragma unroll
      for (int r = 0; r < 4; ++r) mx = fmaxf(mx, s[lt][r]);
    mx = fmaxf(mx, __shfl_xor(mx, 16, 64));
    mx = fmaxf(mx, __shfl_xor(mx, 32, 64));

    float sum = 0.f;
    s16x4 pb[9];
#pragma unroll
    for (int lt = 0; lt < 9; ++lt) {
      float4 ev;
      ev.x = __expf(s[lt][0] - mx); ev.y = __expf(s[lt][1] - mx);
      ev.z = __expf(s[lt][2] - mx); ev.w = __expf(s[lt][3] - mx);
      sum += ev.x + ev.y + ev.z + ev.w;
      pb[lt] = pack4(ev);
    }
    sum += __shfl_xor(sum, 16, 64);
    sum += __shfl_xor(sum, 32, 64);
    const float inv = 1.0f / sum;

    f32x4 o0 = zero, o1 = zero;
#pragma unroll
    for (int lc = 0; lc < 9; ++lc) {
      o0 = __builtin_amdgcn_mfma_f32_16x16x16bf16_1k(vt[0][lc], pb[lc], o0, 0, 0, 0);
      o1 = __builtin_amdgcn_mfma_f32_16x16x16bf16_1k(vt[1][lc], pb[lc], o1, 0, 0, 0);
    }

    float* orow = Sn + (size_t)(qt * 16 + col) * CC;
    *(float4*)&orow[quad * 4] =
        make_float4(o0[0] * inv, o0[1] * inv, o0[2] * inv, o0[3] * inv);
    *(float4*)&orow[16 + quad * 4] =
        make_float4(o1[0] * inv, o1[1] * inv, o1[2] * inv, o1[3] * inv);
  }
}

// ---------------------------------------------------------------------------
// K5: depthwise 3x3 RPE (+bias) added into S. One block per (b,c) plane.
// ---------------------------------------------------------------------------
__global__ __launch_bounds__(256) void k_rpe(const float* __restrict__ x,
                                             const float* __restrict__ rw,
                                             const float* __restrict__ rb,
                                             float* __restrict__ S) {
  const int bc = blockIdx.x;
  const int c = bc & 255;
  const int t = threadIdx.x;
  __shared__ float xs[HWSZ];
  const float* xp = x + (size_t)bc * HWSZ;
  float* sp = S + (size_t)bc * HWSZ;
#pragma unroll
  for (int u = 0; u < 36; ++u) xs[t + 256 * u] = xp[t + 256 * u];
  float w9[9];
#pragma unroll
  for (int k = 0; k < 9; ++k) w9[k] = rw[c * 9 + k];
  const float bias = rb[c];
  __syncthreads();
  for (int u = 0; u < 36; ++u) {
    int idx = t + 256 * u;
    int hh = idx / 96, ww = idx - hh * 96;
    float s = bias;
#pragma unroll
    for (int di = 0; di < 3; ++di) {
      int h2 = hh + di - 1;
#pragma unroll
      for (int dj = 0; dj < 3; ++dj) {
        int w2 = ww + dj - 1;
        if ((unsigned)h2 < 96u && (unsigned)w2 < 96u)
          s += xs[h2 * 96 + w2] * w9[di * 3 + dj];
      }
    }
    sp[idx] += s;
  }
}

// ---------------------------------------------------------------------------
// K6 (MFMA): projection, in-place on d_out. Block = 64 rows x 256 cols.
// ---------------------------------------------------------------------------
__global__ __launch_bounds__(256) void k_proj(const short* __restrict__ pjwb,
                                              const float* __restrict__ pjb,
                                              float* __restrict__ S) {
  const int t = threadIdx.x, lane = t & 63, w = t >> 6;
  const int col = lane & 15, quad = lane >> 4;
  const size_t row0 = (size_t)blockIdx.x * 64;

  __shared__ short Sl[64][264];
  const float* Sp = S + row0 * CC;
#pragma unroll
  for (int u = 0; u < 16; ++u) {
    int idx = u * 1024 + t * 4;
    float4 v = *(const float4*)&Sp[idx];
    *(s16x4*)&Sl[idx >> 8][idx & 255] = pack4(v);
  }
  __syncthreads();

  f32x4 acc[4][4] = {};
  for (int kc = 0; kc < 8; ++kc) {
    bf16x8 bfr[4];
#pragma unroll
    for (int ot = 0; ot < 4; ++ot) {
      s16x8 r = *(const s16x8*)(pjwb + (size_t)(w * 64 + ot * 16 + col) * CC + kc * 32 + quad * 8);
      bfr[ot] = __builtin_bit_cast(bf16x8, r);
    }
#pragma unroll
    for (int mt = 0; mt < 4; ++mt) {
      s16x8 ra = *(const s16x8*)&Sl[mt * 16 + col][kc * 32 + quad * 8];
      bf16x8 af = __builtin_bit_cast(bf16x8, ra);
#pragma unroll
      for (int ot = 0; ot < 4; ++ot)
        acc[mt][ot] = __builtin_amdgcn_mfma_f32_16x16x32_bf16(af, bfr[ot], acc[mt][ot], 0, 0, 0);
    }
  }

  float bias[4];
#pragma unroll
  for (int ot = 0; ot < 4; ++ot) bias[ot] = pjb[w * 64 + ot * 16 + col];
  float* Sw = S + row0 * CC;
#pragma unroll
  for (int mt = 0; mt < 4; ++mt)
#pragma unroll
    for (int ot = 0; ot < 4; ++ot)
#pragma unroll
      for (int r = 0; r < 4; ++r)
        Sw[(mt * 16 + quad * 4 + r) * CC + w * 64 + ot * 16 + col] = acc[mt][ot][r] + bias[ot];
}

// ---------------------------------------------------------------------------
extern "C" void kernel_launch(void* const* d_in, const int* in_sizes, int n_in,
                              void* d_out, int out_size, void* d_ws, size_t ws_size,
                              hipStream_t stream) {
  const float* x    = (const float*)d_in[0];
  const float* wq   = (const float*)d_in[1];
  const float* wkv  = (const float*)d_in[2];
  const float* pw   = (const float*)d_in[3];
  const float* pbv  = (const float*)d_in[4];
  const float* rw   = (const float*)d_in[5];
  const float* rb   = (const float*)d_in[6];
  const float* pjw  = (const float*)d_in[7];
  const float* pjb  = (const float*)d_in[8];
  float* out = (float*)d_out;
  float* ws  = (float*)d_ws;

  float* pxr  = ws;                               // 1152*256 f
  float* kbuf = pxr + CN * CC;                    // 8*8*144*32 f
  float* vbuf = kbuf + CB * NHEADS * CL * HD;     // 8*8*144*32 f
  short* pw2  = (short*)(vbuf + CB * NHEADS * CL * HD);  // 4194304 sh
  short* wqb  = pw2 + 4194304;                    // 65536 sh
  short* pjwb = wqb + 65536;                      // 65536 sh

  // split-K partials live in d_out (37.7 MB <= 75.5 MB), consumed by k_poolred
  // before k_q overwrites d_out.
  float* part = out;

  k_cvtp   <<<2048, 256, 0, stream>>>(pw, pw2);
  k_cvt    <<<32,   256, 0, stream>>>(wq,  wqb,  8192);
  k_cvt    <<<32,   256, 0, stream>>>(pjw, pjwb, 8192);

  k_pool   <<<dim3(36, NSLICE), 256, 0, stream>>>(x, pw2, part);
  k_poolred<<<288,            256, 0, stream>>>(part, pbv, pxr);
  k_kv     <<<dim3(18, 8),    256, 0, stream>>>(pxr, wkv, kbuf, vbuf);
  k_q      <<<CN,             256, 0, stream>>>(x, wqb, out);
  k_attn   <<<CN,             512, 0, stream>>>(kbuf, vbuf, out);
  k_rpe    <<<CB * CC,        256, 0, stream>>>(x, rw, rb, out);
  k_proj   <<<1152,           256, 0, stream>>>(pjwb, pjb, out);
}

// Round 6
// 428.295 us; speedup vs baseline: 1.0549x; 1.0549x over previous
//
#include <hip/hip_runtime.h>
#include <hip/hip_bf16.h>
#include <math.h>

#define CB 8
#define CC 256
#define CH 96
#define CWD 96
#define CL 144           // windows per image (12*12)
#define CN 1152          // total windows
#define CQ 64            // queries per window (8*8)
#define NHEADS 8
#define HD 32
#define HWSZ (CH*CWD)    // 9216
#define QSCALE 0.17677669529663687f   // 32^-0.5
#define NSLICE 32        // pool split-K slices (8 channels each)

typedef __attribute__((ext_vector_type(4))) float  f32x4;
typedef __attribute__((ext_vector_type(4))) short  s16x4;
typedef __attribute__((ext_vector_type(8))) short  s16x8;
typedef __attribute__((ext_vector_type(8))) __bf16 bf16x8;

// native RNE fp32 -> bf16 (v_cvt_pk_bf16_f32 on gfx950)
static __device__ __forceinline__ short f2b(float f) {
  __hip_bfloat16 h = __float2bfloat16(f);
  return __builtin_bit_cast(short, h);
}

static __device__ __forceinline__ bf16x8 pack8(float4 lo, float4 hi) {
  union { __hip_bfloat162 h2[4]; s16x8 v; } u;
  u.h2[0] = __float22bfloat162_rn(make_float2(lo.x, lo.y));
  u.h2[1] = __float22bfloat162_rn(make_float2(lo.z, lo.w));
  u.h2[2] = __float22bfloat162_rn(make_float2(hi.x, hi.y));
  u.h2[3] = __float22bfloat162_rn(make_float2(hi.z, hi.w));
  return __builtin_bit_cast(bf16x8, u.v);
}

static __device__ __forceinline__ s16x4 pack4(float4 v) {
  union { __hip_bfloat162 h2[2]; s16x4 v; } u;
  u.h2[0] = __float22bfloat162_rn(make_float2(v.x, v.y));
  u.h2[1] = __float22bfloat162_rn(make_float2(v.z, v.w));
  return u.v;
}

// ---------------------------------------------------------------------------
// K0: fp32 -> bf16 bulk convert (8 elems / thread)
// ---------------------------------------------------------------------------
__global__ __launch_bounds__(256) void k_cvt(const float* __restrict__ s,
                                             short* __restrict__ d, int n8) {
  int i = blockIdx.x * 256 + threadIdx.x;
  if (i >= n8) return;
  const float4* p = (const float4*)s + (size_t)i * 2;
  *(s16x8*)(d + (size_t)i * 8) = __builtin_bit_cast(s16x8, pack8(p[0], p[1]));
}

// ---------------------------------------------------------------------------
// K0b: pool_w -> bf16, K-blocked fragment-native layout.
//   pw2[((ks*16 + kc)*256 + o)*32 + kk] = bf16( pw[o][ks*512 + kc*32 + kk] )
// ---------------------------------------------------------------------------
__global__ __launch_bounds__(256) void k_cvtp(const float* __restrict__ pw,
                                              short* __restrict__ pw2) {
  int g = blockIdx.x * 256 + threadIdx.x;      // 524288 groups of 8
  int kk8 = (g & 3) * 8;
  int o   = (g >> 2) & 255;
  int kc  = (g >> 10) & 15;
  int ks  = g >> 14;
  int kglob = ks * 512 + kc * 32 + kk8;
  const float* src = pw + (size_t)o * 16384 + kglob;  // 8 contiguous floats
  *(s16x8*)(pw2 + (size_t)g * 8) =
      __builtin_bit_cast(s16x8, pack8(*(const float4*)src, *(const float4*)(src + 4)));
}

// ---------------------------------------------------------------------------
// K0c: kbuf/vbuf fp32 -> bf16 once (L2-hot), hoisting conversion out of attn.
//   kbt[b,h][l][d]  (same layout, bf16)
//   vbt[b,h][d][l]  (transposed -> V^T A-frag loads become contiguous 8B)
//   36864 threads, 8 elems each.
// ---------------------------------------------------------------------------
__global__ __launch_bounds__(256) void k_cvtkv(const float* __restrict__ kbuf,
                                               const float* __restrict__ vbuf,
                                               short* __restrict__ kbt,
                                               short* __restrict__ vbt) {
  int i = blockIdx.x * 256 + threadIdx.x;      // 144 blocks * 256 = 36864
  const float4* kp = (const float4*)kbuf + (size_t)i * 2;
  *(s16x8*)(kbt + (size_t)i * 8) = __builtin_bit_cast(s16x8, pack8(kp[0], kp[1]));

  int l8 = i % 18, rest = i / 18;              // i = (bh*32 + d)*18 + l8
  int d = rest & 31, bh = rest >> 5;
  const float* vp = vbuf + ((size_t)bh * CL + l8 * 8) * HD + d;
  float4 a, b;
  a.x = vp[0];   a.y = vp[32];  a.z = vp[64];  a.w = vp[96];
  b.x = vp[128]; b.y = vp[160]; b.z = vp[192]; b.w = vp[224];
  *(s16x8*)(vbt + (size_t)i * 8) = __builtin_bit_cast(s16x8, pack8(a, b));
}

// ---------------------------------------------------------------------------
// K1 (MFMA v4): pool partial GEMM, split-K x32.
//   grid (36 rowblk, 32 kslice) = 1152 blocks. Block = 32 windows x 256 cols.
//   Waves COLUMN-split: B-frags unique per wave, A shared via L1.
// ---------------------------------------------------------------------------
__global__ __launch_bounds__(256) void k_pool(const float* __restrict__ x,
                                              const short* __restrict__ pw2,
                                              float* __restrict__ part) {
  const int t = threadIdx.x, lane = t & 63, w = t >> 6;
  const int col = lane & 15, quad = lane >> 4;
  const int mb = blockIdx.x, ks = blockIdx.y;

  size_t xbase[2];
#pragma unroll
  for (int rt = 0; rt < 2; ++rt) {
    int wdx = mb * 32 + rt * 16 + col;
    int b = wdx / CL, l = wdx - b * CL;
    int wh = l / 12, ww = l - wh * 12;
    xbase[rt] = (size_t)b * CC * HWSZ + wh * 8 * CWD + ww * 8;
  }

  f32x4 acc[2][4] = {};

#pragma unroll 4
  for (int kc = 0; kc < 16; ++kc) {
    const int c = ks * 8 + (kc >> 1);
    const int i = (kc & 1) * 4 + quad;
    bf16x8 af[2];
#pragma unroll
    for (int rt = 0; rt < 2; ++rt) {
      const float* ap = x + xbase[rt] + (size_t)c * HWSZ + i * CWD;
      af[rt] = pack8(*(const float4*)ap, *(const float4*)(ap + 4));
    }
    const short* bk = pw2 + ((size_t)(ks * 16 + kc) * 256 + w * 64) * 32;
#pragma unroll
    for (int ct = 0; ct < 4; ++ct) {
      s16x8 rb = *(const s16x8*)(bk + (ct * 16 + col) * 32 + quad * 8);
      bf16x8 bf = __builtin_bit_cast(bf16x8, rb);
#pragma unroll
      for (int rt = 0; rt < 2; ++rt)
        acc[rt][ct] = __builtin_amdgcn_mfma_f32_16x16x32_bf16(af[rt], bf, acc[rt][ct], 0, 0, 0);
    }
  }

  float* pp = part + ((size_t)ks * CN + mb * 32) * CC + w * 64;
#pragma unroll
  for (int rt = 0; rt < 2; ++rt)
#pragma unroll
    for (int ct = 0; ct < 4; ++ct)
#pragma unroll
      for (int r = 0; r < 4; ++r)
        pp[(rt * 16 + quad * 4 + r) * CC + ct * 16 + col] = acc[rt][ct][r];
}

// ---------------------------------------------------------------------------
// K1b: reduce 32 partials + bias -> pxr[1152][256]
// ---------------------------------------------------------------------------
__global__ __launch_bounds__(256) void k_poolred(const float* __restrict__ part,
                                                 const float* __restrict__ pbv,
                                                 float* __restrict__ pxr) {
  int base = (blockIdx.x * 256 + threadIdx.x) * 4;
  int m = base & 255;
  float4 s = *(const float4*)&pbv[m];
#pragma unroll
  for (int ss = 0; ss < NSLICE; ++ss) {
    float4 p = *(const float4*)&part[(size_t)ss * (CN * CC) + base];
    s.x += p.x; s.y += p.y; s.z += p.z; s.w += p.w;
  }
  *(float4*)&pxr[base] = s;
}

// ---------------------------------------------------------------------------
// K2: kv GEMM [1152,256] @ Wkv^T -> scatter to k[b,h,l,d], v[b,h,l,d]  (fp32)
// ---------------------------------------------------------------------------
__global__ __launch_bounds__(256) void k_kv(const float* __restrict__ pxr,
                                            const float* __restrict__ wkv,
                                            float* __restrict__ kbuf,
                                            float* __restrict__ vbuf) {
  const int t = threadIdx.x, tx = t & 15, ty = t >> 4;
  const int row0 = blockIdx.x * 64;
  const int col0 = blockIdx.y * 64;
  __shared__ float As[16][68];
  __shared__ float Bs[16][68];
  float acc[4][4] = {};
  const int ml = t & 15, rB = t >> 4;

  for (int mc = 0; mc < 16; ++mc) {
#pragma unroll
    for (int u = 0; u < 4; ++u) {
      int r = rB + 16 * u;
      As[ml][r] = pxr[(row0 + r) * CC + mc * 16 + ml];
      Bs[ml][r] = wkv[(col0 + r) * CC + mc * 16 + ml];
    }
    __syncthreads();
#pragma unroll
    for (int kk = 0; kk < 16; ++kk) {
      float4 a4 = *(const float4*)&As[kk][ty * 4];
      float4 b4 = *(const float4*)&Bs[kk][tx * 4];
      float av[4] = {a4.x, a4.y, a4.z, a4.w};
      float bv[4] = {b4.x, b4.y, b4.z, b4.w};
#pragma unroll
      for (int ri = 0; ri < 4; ++ri)
#pragma unroll
        for (int cj = 0; cj < 4; ++cj) acc[ri][cj] += av[ri] * bv[cj];
    }
    __syncthreads();
  }

#pragma unroll
  for (int ri = 0; ri < 4; ++ri) {
    int row = row0 + ty * 4 + ri;
    int b = row / CL, l = row - b * CL;
    int j = col0 + tx * 4;
    int d = j & 31, h = (j >> 5) & 7, tkv = j >> 8;
    float* dst = (tkv ? vbuf : kbuf) + ((size_t)(b * NHEADS + h) * CL + l) * HD + d;
    *(float4*)dst = make_float4(acc[ri][0], acc[ri][1], acc[ri][2], acc[ri][3]);
  }
}

// ---------------------------------------------------------------------------
// K3 (MFMA): q^T = Wq * xw^T per window; C-layout store transposes back into
//   d_out q slots.
// ---------------------------------------------------------------------------
__global__ __launch_bounds__(256) void k_q(const float* __restrict__ x,
                                           const short* __restrict__ wqb,
                                           float* __restrict__ qout) {
  const int t = threadIdx.x, lane = t & 63, w = t >> 6;
  const int col = lane & 15, quad = lane >> 4;
  const int n = blockIdx.x;
  const int b = n / CL, l = n - b * CL;
  const int wh = l / 12, ww = l - wh * 12;
  const size_t xwin = (size_t)b * CC * HWSZ + wh * 8 * CWD + ww * 8;

  __shared__ short xq[64][264];
  {
    const int ci = t & 31, ii = t >> 5;
#pragma unroll
    for (int u = 0; u < 8; ++u) {
      const float* ap = x + xwin + (size_t)(ci + 32 * u) * HWSZ + ii * CWD;
      float4 lo = *(const float4*)ap, hi = *(const float4*)(ap + 4);
      float vals[8] = {lo.x, lo.y, lo.z, lo.w, hi.x, hi.y, hi.z, hi.w};
#pragma unroll
      for (int j = 0; j < 8; ++j) xq[ii * 8 + j][ci + 32 * u] = f2b(vals[j]);
    }
  }
  __syncthreads();

  f32x4 acc[4][4] = {};
  for (int kc = 0; kc < 8; ++kc) {
    bf16x8 af[4];
#pragma unroll
    for (int cht = 0; cht < 4; ++cht) {
      s16x8 r = *(const s16x8*)(wqb + (size_t)(w * 64 + cht * 16 + col) * CC + kc * 32 + quad * 8);
      af[cht] = __builtin_bit_cast(bf16x8, r);
    }
#pragma unroll
    for (int qt = 0; qt < 4; ++qt) {
      s16x8 rb = *(const s16x8*)&xq[qt * 16 + col][kc * 32 + quad * 8];
      bf16x8 bfv = __builtin_bit_cast(bf16x8, rb);
#pragma unroll
      for (int cht = 0; cht < 4; ++cht)
        acc[cht][qt] = __builtin_amdgcn_mfma_f32_16x16x32_bf16(af[cht], bfv, acc[cht][qt], 0, 0, 0);
    }
  }

  float* op = qout + (size_t)n * CQ * CC;
#pragma unroll
  for (int qt = 0; qt < 4; ++qt)
#pragma unroll
    for (int cht = 0; cht < 4; ++cht) {
      f32x4 v = acc[cht][qt];
      *(float4*)&op[(qt * 16 + col) * CC + w * 64 + cht * 16 + quad * 4] =
          make_float4(v[0] * QSCALE, v[1] * QSCALE, v[2] * QSCALE, v[3] * QSCALE);
    }
}

// ---------------------------------------------------------------------------
// K4 (MFMA v4): attention. Block = 1 window x 512 threads (8 waves = 8 heads).
//   K/V pre-converted bf16 (kbt [l][d], vbt [d][l]) -> frag loads are direct.
// ---------------------------------------------------------------------------
__global__ __launch_bounds__(512) void k_attn(const short* __restrict__ kbt,
                                              const short* __restrict__ vbt,
                                              float* __restrict__ S) {
  const int t = threadIdx.x;
  const int h = t >> 6, lane = t & 63;
  const int col = lane & 15, quad = lane >> 4;
  const int n = blockIdx.x;
  const int bb = n & 7;

  const short* kh = kbt + (size_t)(bb * NHEADS + h) * CL * HD;
  const short* vh = vbt + (size_t)(bb * NHEADS + h) * HD * CL;
  float* Sn = S + (size_t)n * (CQ * CC) + h * HD;

  bf16x8 ka[9];
#pragma unroll
  for (int lt = 0; lt < 9; ++lt)
    ka[lt] = __builtin_bit_cast(bf16x8, *(const s16x8*)(kh + (lt * 16 + col) * HD + quad * 8));

  s16x4 vt[2][9];
#pragma unroll
  for (int dt = 0; dt < 2; ++dt)
#pragma unroll
    for (int lc = 0; lc < 9; ++lc)
      vt[dt][lc] = *(const s16x4*)(vh + (dt * 16 + col) * CL + lc * 16 + quad * 4);

  const f32x4 zero = {0.f, 0.f, 0.f, 0.f};

#pragma unroll
  for (int qt = 0; qt < 4; ++qt) {
    const float* qr = Sn + (size_t)(qt * 16 + col) * CC + quad * 8;
    bf16x8 qb = pack8(*(const float4*)qr, *(const float4*)(qr + 4));

    f32x4 s[9];
#pragma unroll
    for (int lt = 0; lt < 9; ++lt)
      s[lt] = __builtin_amdgcn_mfma_f32_16x16x32_bf16(ka[lt], qb, zero, 0, 0, 0);

    float mx = s[0][0];
#pragma unroll
    for (int lt = 0; lt < 9; ++lt)
#pragma unroll
      for (int r = 0; r < 4; ++r) mx = fmaxf(mx, s[lt][r]);
    mx = fmaxf(mx, __shfl_xor(mx, 16, 64));
    mx = fmaxf(mx, __shfl_xor(mx, 32, 64));

    float sum = 0.f;
    s16x4 pb[9];
#pragma unroll
    for (int lt = 0; lt < 9; ++lt) {
      float4 ev;
      ev.x = __expf(s[lt][0] - mx); ev.y = __expf(s[lt][1] - mx);
      ev.z = __expf(s[lt][2] - mx); ev.w = __expf(s[lt][3] - mx);
      sum += ev.x + ev.y + ev.z + ev.w;
      pb[lt] = pack4(ev);
    }
    sum += __shfl_xor(sum, 16, 64);
    sum += __shfl_xor(sum, 32, 64);
    const float inv = 1.0f / sum;

    f32x4 o0 = zero, o1 = zero;
#pragma unroll
    for (int lc = 0; lc < 9; ++lc) {
      o0 = __builtin_amdgcn_mfma_f32_16x16x16bf16_1k(vt[0][lc], pb[lc], o0, 0, 0, 0);
      o1 = __builtin_amdgcn_mfma_f32_16x16x16bf16_1k(vt[1][lc], pb[lc], o1, 0, 0, 0);
    }

    float* orow = Sn + (size_t)(qt * 16 + col) * CC;
    *(float4*)&orow[quad * 4] =
        make_float4(o0[0] * inv, o0[1] * inv, o0[2] * inv, o0[3] * inv);
    *(float4*)&orow[16 + quad * 4] =
        make_float4(o1[0] * inv, o1[1] * inv, o1[2] * inv, o1[3] * inv);
  }
}

// ---------------------------------------------------------------------------
// K5: depthwise 3x3 RPE (+bias) added into S. One block per (b,c) plane.
// ---------------------------------------------------------------------------
__global__ __launch_bounds__(256) void k_rpe(const float* __restrict__ x,
                                             const float* __restrict__ rw,
                                             const float* __restrict__ rb,
                                             float* __restrict__ S) {
  const int bc = blockIdx.x;
  const int c = bc & 255;
  const int t = threadIdx.x;
  __shared__ float xs[HWSZ];
  const float* xp = x + (size_t)bc * HWSZ;
  float* sp = S + (size_t)bc * HWSZ;
#pragma unroll
  for (int u = 0; u < 36; ++u) xs[t + 256 * u] = xp[t + 256 * u];
  float w9[9];
#pragma unroll
  for (int k = 0; k < 9; ++k) w9[k] = rw[c * 9 + k];
  const float bias = rb[c];
  __syncthreads();
  for (int u = 0; u < 36; ++u) {
    int idx = t + 256 * u;
    int hh = idx / 96, ww = idx - hh * 96;
    float s = bias;
#pragma unroll
    for (int di = 0; di < 3; ++di) {
      int h2 = hh + di - 1;
#pragma unroll
      for (int dj = 0; dj < 3; ++dj) {
        int w2 = ww + dj - 1;
        if ((unsigned)h2 < 96u && (unsigned)w2 < 96u)
          s += xs[h2 * 96 + w2] * w9[di * 3 + dj];
      }
    }
    sp[idx] += s;
  }
}

// ---------------------------------------------------------------------------
// K6 (MFMA): projection, in-place on d_out. Block = 64 rows x 256 cols.
// ---------------------------------------------------------------------------
__global__ __launch_bounds__(256) void k_proj(const short* __restrict__ pjwb,
                                              const float* __restrict__ pjb,
                                              float* __restrict__ S) {
  const int t = threadIdx.x, lane = t & 63, w = t >> 6;
  const int col = lane & 15, quad = lane >> 4;
  const size_t row0 = (size_t)blockIdx.x * 64;

  __shared__ short Sl[64][264];
  const float* Sp = S + row0 * CC;
#pragma unroll
  for (int u = 0; u < 16; ++u) {
    int idx = u * 1024 + t * 4;
    float4 v = *(const float4*)&Sp[idx];
    *(s16x4*)&Sl[idx >> 8][idx & 255] = pack4(v);
  }
  __syncthreads();

  f32x4 acc[4][4] = {};
  for (int kc = 0; kc < 8; ++kc) {
    bf16x8 bfr[4];
#pragma unroll
    for (int ot = 0; ot < 4; ++ot) {
      s16x8 r = *(const s16x8*)(pjwb + (size_t)(w * 64 + ot * 16 + col) * CC + kc * 32 + quad * 8);
      bfr[ot] = __builtin_bit_cast(bf16x8, r);
    }
#pragma unroll
    for (int mt = 0; mt < 4; ++mt) {
      s16x8 ra = *(const s16x8*)&Sl[mt * 16 + col][kc * 32 + quad * 8];
      bf16x8 af = __builtin_bit_cast(bf16x8, ra);
#pragma unroll
      for (int ot = 0; ot < 4; ++ot)
        acc[mt][ot] = __builtin_amdgcn_mfma_f32_16x16x32_bf16(af, bfr[ot], acc[mt][ot], 0, 0, 0);
    }
  }

  float bias[4];
#pragma unroll
  for (int ot = 0; ot < 4; ++ot) bias[ot] = pjb[w * 64 + ot * 16 + col];
  float* Sw = S + row0 * CC;
#pragma unroll
  for (int mt = 0; mt < 4; ++mt)
#pragma unroll
    for (int ot = 0; ot < 4; ++ot)
#pragma unroll
      for (int r = 0; r < 4; ++r)
        Sw[(mt * 16 + quad * 4 + r) * CC + w * 64 + ot * 16 + col] = acc[mt][ot][r] + bias[ot];
}

// ---------------------------------------------------------------------------
extern "C" void kernel_launch(void* const* d_in, const int* in_sizes, int n_in,
                              void* d_out, int out_size, void* d_ws, size_t ws_size,
                              hipStream_t stream) {
  const float* x    = (const float*)d_in[0];
  const float* wq   = (const float*)d_in[1];
  const float* wkv  = (const float*)d_in[2];
  const float* pw   = (const float*)d_in[3];
  const float* pbv  = (const float*)d_in[4];
  const float* rw   = (const float*)d_in[5];
  const float* rb   = (const float*)d_in[6];
  const float* pjw  = (const float*)d_in[7];
  const float* pjb  = (const float*)d_in[8];
  float* out = (float*)d_out;
  float* ws  = (float*)d_ws;

  float* pxr  = ws;                               // 1152*256 f
  float* kbuf = pxr + CN * CC;                    // 8*8*144*32 f
  float* vbuf = kbuf + CB * NHEADS * CL * HD;     // 8*8*144*32 f
  short* pw2  = (short*)(vbuf + CB * NHEADS * CL * HD);  // 4194304 sh
  short* wqb  = pw2 + 4194304;                    // 65536 sh
  short* pjwb = wqb + 65536;                      // 65536 sh
  short* kbt  = pjwb + 65536;                     // 294912 sh
  short* vbt  = kbt + 294912;                     // 294912 sh

  // split-K partials live in d_out (37.7 MB <= 75.5 MB), consumed by k_poolred
  // before k_q overwrites d_out.
  float* part = out;

  k_cvtp   <<<2048, 256, 0, stream>>>(pw, pw2);
  k_cvt    <<<32,   256, 0, stream>>>(wq,  wqb,  8192);
  k_cvt    <<<32,   256, 0, stream>>>(pjw, pjwb, 8192);

  k_pool   <<<dim3(36, NSLICE), 256, 0, stream>>>(x, pw2, part);
  k_poolred<<<288,            256, 0, stream>>>(part, pbv, pxr);
  k_kv     <<<dim3(18, 8),    256, 0, stream>>>(pxr, wkv, kbuf, vbuf);
  k_cvtkv  <<<144,            256, 0, stream>>>(kbuf, vbuf, kbt, vbt);
  k_q      <<<CN,             256, 0, stream>>>(x, wqb, out);
  k_attn   <<<CN,             512, 0, stream>>>(kbt, vbt, out);
  k_rpe    <<<CB * CC,        256, 0, stream>>>(x, rw, rb, out);
  k_proj   <<<1152,           256, 0, stream>>>(pjwb, pjb, out);
}